// Round 1
// baseline (31.890 us; speedup 1.0000x reference)
//
#include <hip/hip_runtime.h>

// Problem constants: B=16, C=3, H=W=512, PATCH=16, Hp=Wp=32
#define N_PIX   4194304      // B*H*W = 16*512*512
#define HW      262144       // 512*512 (one channel plane)
#define CHW     786432       // 3*512*512 (one image)
#define NV      16384        // B*Hp*Wp

// Output layout (flat float32 element offsets, concatenated in return order):
//   fV  [N_PIX, 3]   at 0          (12582912)
//   seg [N_PIX]      at 12582912   (4194304)
//   byx [3, N_PIX]   at 16777216   (12582912)
//   bb  [4, NV]      at 29360128   (65536)
#define FV_OFF   0
#define SEG_OFF  12582912
#define BYX_OFF  16777216
#define BB_OFF   29360128

__global__ __launch_bounds__(256)
void vit_patch_tok_kernel(const float* __restrict__ img, float* __restrict__ out) {
    const int t  = blockIdx.x * blockDim.x + threadIdx.x;  // 0 .. 1048575
    const int p0 = t << 2;                                  // base pixel (4 pixels/thread)

    const int b   = p0 >> 18;          // pixel / (H*W)
    const int rem = p0 & (HW - 1);
    const int y   = rem >> 9;          // / W
    const int x0  = rem & 511;         // % W  (multiple of 4)

    // ---- read 4 pixels from each channel plane (aligned float4, coalesced) ----
    const float* base = img + (size_t)b * CHW + y * 512 + x0;
    const float4 r  = *reinterpret_cast<const float4*>(base);
    const float4 g  = *reinterpret_cast<const float4*>(base + HW);
    const float4 bl = *reinterpret_cast<const float4*>(base + 2 * HW);

    // ---- fV: NHWC interleave, 12 contiguous floats = 3 aligned float4 ----
    float4* fv = reinterpret_cast<float4*>(out + FV_OFF + 3 * p0);
    fv[0] = make_float4(r.x,  g.x,  bl.x, r.y);
    fv[1] = make_float4(g.y,  bl.y, r.z,  g.z);
    fv[2] = make_float4(bl.z, r.w,  g.w,  bl.w);

    // ---- seg: b*1024 + (y>>4)*32 + (x>>4); constant across the 4 pixels
    // (x0 ≡ 0 mod 4 so x0..x0+3 never cross a 16-boundary) ----
    const float segv = (float)(b * 1024 + (y >> 4) * 32 + (x0 >> 4));
    *reinterpret_cast<float4*>(out + SEG_OFF + p0) = make_float4(segv, segv, segv, segv);

    // ---- byx rows (b, y, x) ----
    const float fb = (float)b, fy = (float)y;
    *reinterpret_cast<float4*>(out + BYX_OFF + p0) =
        make_float4(fb, fb, fb, fb);
    *reinterpret_cast<float4*>(out + BYX_OFF + N_PIX + p0) =
        make_float4(fy, fy, fy, fy);
    *reinterpret_cast<float4*>(out + BYX_OFF + 2 * N_PIX + p0) =
        make_float4((float)x0, (float)(x0 + 1), (float)(x0 + 2), (float)(x0 + 3));

    // ---- bb: uniform 16x16 squares -> closed-form bbox per segment ----
    if (t < NV) {
        const int py = (t & 1023) >> 5;   // (s % (Hp*Wp)) / Wp
        const int px = t & 31;            // s % Wp
        out[BB_OFF + t]          = (float)(py * 16);        // ymin
        out[BB_OFF + NV + t]     = (float)(px * 16);        // xmin
        out[BB_OFF + 2 * NV + t] = (float)(py * 16 + 15);   // ymax
        out[BB_OFF + 3 * NV + t] = (float)(px * 16 + 15);   // xmax
    }
}

extern "C" void kernel_launch(void* const* d_in, const int* in_sizes, int n_in,
                              void* d_out, int out_size, void* d_ws, size_t ws_size,
                              hipStream_t stream) {
    const float* img = reinterpret_cast<const float*>(d_in[0]);
    float* out = reinterpret_cast<float*>(d_out);

    const int threads = N_PIX / 4;            // 1048576
    const int block = 256;
    const int grid = threads / block;         // 4096
    vit_patch_tok_kernel<<<grid, block, 0, stream>>>(img, out);
}

// Round 2
// 29.549 us; speedup vs baseline: 1.0792x; 1.0792x over previous
//
#include <hip/hip_runtime.h>

// Problem constants: B=16, C=3, H=W=512, PATCH=16, Hp=Wp=32
#define N_PIX   4194304      // B*H*W = 16*512*512
#define HW      262144       // 512*512 (one channel plane)
#define CHW     786432       // 3*512*512 (one image)
#define NV      16384        // B*Hp*Wp

// Output layout (flat float32 element offsets, concatenated in return order):
//   fV  [N_PIX, 3]   at 0          (12582912)
//   seg [N_PIX]      at 12582912   (4194304)
//   byx [3, N_PIX]   at 16777216   (12582912)
//   bb  [4, NV]      at 29360128   (65536)
#define FV_OFF   0
#define SEG_OFF  12582912
#define BYX_OFF  16777216
#define BB_OFF   29360128

__global__ __launch_bounds__(256)
void vit_patch_tok_kernel(const float* __restrict__ img, float* __restrict__ out) {
    // 768 float4 = 12 KB: staging buffer so fV global stores are lane-contiguous.
    __shared__ float4 lds[768];

    const int tid = threadIdx.x;
    const int t   = blockIdx.x * 256 + tid;   // 0 .. 1048575
    const int p0  = t << 2;                   // base pixel (4 pixels/thread)

    const int b   = p0 >> 18;          // pixel / (H*W)
    const int rem = p0 & (HW - 1);
    const int y   = rem >> 9;          // / W
    const int x0  = rem & 511;         // % W  (multiple of 4)

    // ---- read 4 pixels from each channel plane (aligned float4, coalesced) ----
    const float* base = img + (size_t)b * CHW + y * 512 + x0;
    const float4 r  = *reinterpret_cast<const float4*>(base);
    const float4 g  = *reinterpret_cast<const float4*>(base + HW);
    const float4 bl = *reinterpret_cast<const float4*>(base + 2 * HW);

    // ---- stage NHWC-interleaved fV into LDS ----
    // write: byte addr = tid*48 (+0/16/32). Lanes 0..7 cover all 32 banks
    // disjointly per b128 phase -> conflict-free.
    lds[tid * 3 + 0] = make_float4(r.x,  g.x,  bl.x, r.y);
    lds[tid * 3 + 1] = make_float4(g.y,  bl.y, r.z,  g.z);
    lds[tid * 3 + 2] = make_float4(bl.z, r.w,  g.w,  bl.w);

    // ---- seg: b*1024 + (y>>4)*32 + (x>>4); constant across the 4 pixels ----
    const float segv = (float)(b * 1024 + (y >> 4) * 32 + (x0 >> 4));
    *reinterpret_cast<float4*>(out + SEG_OFF + p0) = make_float4(segv, segv, segv, segv);

    // ---- byx rows (b, y, x): all lane-contiguous float4 stores ----
    const float fb = (float)b, fy = (float)y;
    *reinterpret_cast<float4*>(out + BYX_OFF + p0) =
        make_float4(fb, fb, fb, fb);
    *reinterpret_cast<float4*>(out + BYX_OFF + N_PIX + p0) =
        make_float4(fy, fy, fy, fy);
    *reinterpret_cast<float4*>(out + BYX_OFF + 2 * N_PIX + p0) =
        make_float4((float)x0, (float)(x0 + 1), (float)(x0 + 2), (float)(x0 + 3));

    // ---- bb: uniform 16x16 squares -> closed-form bbox per segment ----
    if (t < NV) {
        const int py = (t & 1023) >> 5;   // (s % (Hp*Wp)) / Wp
        const int px = t & 31;            // s % Wp
        out[BB_OFF + t]          = (float)(py * 16);        // ymin
        out[BB_OFF + NV + t]     = (float)(px * 16);        // xmin
        out[BB_OFF + 2 * NV + t] = (float)(py * 16 + 15);   // ymax
        out[BB_OFF + 3 * NV + t] = (float)(px * 16 + 15);   // xmax
    }

    __syncthreads();

    // ---- drain LDS -> global: 3 fully-coalesced float4 stores ----
    // (instr j: block writes float4s [blk*768 + j*256, +256) = 4 KB contiguous)
    float4* fvout = reinterpret_cast<float4*>(out + FV_OFF) + (size_t)blockIdx.x * 768;
    fvout[tid]       = lds[tid];
    fvout[256 + tid] = lds[256 + tid];
    fvout[512 + tid] = lds[512 + tid];
}

extern "C" void kernel_launch(void* const* d_in, const int* in_sizes, int n_in,
                              void* d_out, int out_size, void* d_ws, size_t ws_size,
                              hipStream_t stream) {
    const float* img = reinterpret_cast<const float*>(d_in[0]);
    float* out = reinterpret_cast<float*>(d_out);

    const int threads = N_PIX / 4;            // 1048576
    const int block = 256;
    const int grid = threads / block;         // 4096
    vit_patch_tok_kernel<<<grid, block, 0, stream>>>(img, out);
}

// Round 4
// 29.218 us; speedup vs baseline: 1.0914x; 1.0113x over previous
//
#include <hip/hip_runtime.h>

// Problem constants: B=16, C=3, H=W=512, PATCH=16, Hp=Wp=32
#define N_PIX   4194304      // B*H*W = 16*512*512
#define HW      262144       // 512*512 (one channel plane)
#define CHW     786432       // 3*512*512 (one image)
#define NV      16384        // B*Hp*Wp

// Output layout (flat float32 element offsets, concatenated in return order):
//   fV  [N_PIX, 3]   at 0          (12582912)
//   seg [N_PIX]      at 12582912   (4194304)
//   byx [3, N_PIX]   at 16777216   (12582912)
//   bb  [4, NV]      at 29360128   (65536)
#define FV_OFF   0
#define SEG_OFF  12582912
#define BYX_OFF  16777216
#define BB_OFF   29360128

// Native vector type — __builtin_nontemporal_store requires scalar/ext-vector,
// not HIP's float4 struct.
typedef float vf4 __attribute__((ext_vector_type(4)));

__device__ __forceinline__ void nt_store4(float* p, float a, float b, float c, float d) {
    vf4 v = {a, b, c, d};
    __builtin_nontemporal_store(v, reinterpret_cast<vf4*>(p));
}
__device__ __forceinline__ void nt_store4v(float* p, vf4 v) {
    __builtin_nontemporal_store(v, reinterpret_cast<vf4*>(p));
}

__global__ __launch_bounds__(256)
void vit_patch_tok_kernel(const float* __restrict__ img, float* __restrict__ out) {
    // 768 vf4 = 12 KB: staging buffer so fV global stores are lane-contiguous.
    __shared__ vf4 lds[768];

    const int tid = threadIdx.x;
    const int t   = blockIdx.x * 256 + tid;   // 0 .. 1048575
    const int p0  = t << 2;                   // base pixel (4 pixels/thread)

    const int b   = p0 >> 18;          // pixel / (H*W)
    const int rem = p0 & (HW - 1);
    const int y   = rem >> 9;          // / W
    const int x0  = rem & 511;         // % W  (multiple of 4)

    // ---- read 4 pixels from each channel plane (aligned 16B, coalesced).
    // Plain (cached) loads: img is 50 MB and should stay resident in L3
    // across graph replays once stores stop evicting it. ----
    const float* base = img + (size_t)b * CHW + y * 512 + x0;
    const vf4 r  = *reinterpret_cast<const vf4*>(base);
    const vf4 g  = *reinterpret_cast<const vf4*>(base + HW);
    const vf4 bl = *reinterpret_cast<const vf4*>(base + 2 * HW);

    // ---- stage NHWC-interleaved fV into LDS (conflict-free b128 pattern) ----
    lds[tid * 3 + 0] = (vf4){r.x,  g.x,  bl.x, r.y};
    lds[tid * 3 + 1] = (vf4){g.y,  bl.y, r.z,  g.z};
    lds[tid * 3 + 2] = (vf4){bl.z, r.w,  g.w,  bl.w};

    // ---- seg: b*1024 + (y>>4)*32 + (x>>4); constant across the 4 pixels ----
    const float segv = (float)(b * 1024 + (y >> 4) * 32 + (x0 >> 4));
    nt_store4(out + SEG_OFF + p0, segv, segv, segv, segv);

    // ---- byx rows (b, y, x): lane-contiguous nt stores ----
    const float fb = (float)b, fy = (float)y;
    nt_store4(out + BYX_OFF + p0,             fb, fb, fb, fb);
    nt_store4(out + BYX_OFF + N_PIX + p0,     fy, fy, fy, fy);
    nt_store4(out + BYX_OFF + 2 * N_PIX + p0,
              (float)x0, (float)(x0 + 1), (float)(x0 + 2), (float)(x0 + 3));

    // ---- bb: uniform 16x16 squares -> closed-form bbox per segment ----
    if (t < NV) {
        const int py = (t & 1023) >> 5;   // (s % (Hp*Wp)) / Wp
        const int px = t & 31;            // s % Wp
        __builtin_nontemporal_store((float)(py * 16),      out + BB_OFF + t);
        __builtin_nontemporal_store((float)(px * 16),      out + BB_OFF + NV + t);
        __builtin_nontemporal_store((float)(py * 16 + 15), out + BB_OFF + 2 * NV + t);
        __builtin_nontemporal_store((float)(px * 16 + 15), out + BB_OFF + 3 * NV + t);
    }

    __syncthreads();

    // ---- drain LDS -> global: 3 fully-coalesced nt 16B stores ----
    float* fvout = out + FV_OFF + (size_t)blockIdx.x * 3072;
    nt_store4v(fvout + 4 * tid,        lds[tid]);
    nt_store4v(fvout + 4096 + 4 * tid, lds[256 + tid]);
    nt_store4v(fvout + 8192 + 4 * tid, lds[512 + tid]);
}

extern "C" void kernel_launch(void* const* d_in, const int* in_sizes, int n_in,
                              void* d_out, int out_size, void* d_ws, size_t ws_size,
                              hipStream_t stream) {
    const float* img = reinterpret_cast<const float*>(d_in[0]);
    float* out = reinterpret_cast<float*>(d_out);

    const int threads = N_PIX / 4;            // 1048576
    const int block = 256;
    const int grid = threads / block;         // 4096
    vit_patch_tok_kernel<<<grid, block, 0, stream>>>(img, out);
}